// Round 12
// baseline (557.850 us; speedup 1.0000x reference)
//
#include <hip/hip_runtime.h>

// GraphSAGE mean-aggregate + linear (no bias): out = segment_mean(x[src] by dst) @ W^T
// x: [50000, 64] f32, edge_index: [2, 800000] int32, W: [128, 64] f32,
// out: [50000, 128] f32.
//
// Pipeline (4 dispatches):
//   memset(cursor) -> bin (bucket sort by dst/196, 32-bit packed (dst<<16)|src)
//   -> csr_build (per-bucket local CSR, wave-scans) -> gather_fused
//      (512-thread blocks, 4 nodes/wave: prefetched offs+idx, register gather,
//       single 4-node mean+W^T epilogue from LDS-staged W).

constexpr int N_NODES = 50000;
constexpr int N_EDGES = 800000;
constexpr int IN_CH   = 64;
constexpr int HID_CH  = 128;

constexpr int NBKT          = 256;
constexpr int NODES_PER_BKT = 196;   // 256*196 = 50176 >= 50000; bucket = dst/196
constexpr int BKT_CAP       = 4096;  // mean 3125, sigma ~56 -> +17 sigma headroom
constexpr int CHUNK         = 4096;  // edges per binning block
constexpr int NBIN          = (N_EDGES + CHUNK - 1) / CHUNK;  // 196

// ---- pass 1: bucket-bin edges, 32-bit packed (dst<<16)|src ----
__global__ __launch_bounds__(256) void bin_kernel(
    const int* __restrict__ ei,
    int* __restrict__ cursor,              // [NBKT], zeroed
    unsigned* __restrict__ binned)         // [NBKT][BKT_CAP]
{
    __shared__ int hist[NBKT];
    __shared__ int lexcl[NBKT];
    __shared__ int lcur[NBKT];
    __shared__ int res[NBKT];
    __shared__ int wsum[4];
    __shared__ unsigned stage[CHUNK];      // 16 KB

    const int t    = threadIdx.x;
    const int wave = t >> 6;
    const int lane = t & 63;
    const int e0   = blockIdx.x * CHUNK;
    const int nE   = min(N_EDGES - e0, CHUNK);

    hist[t] = 0;
    __syncthreads();

    int srcs[16], dsts[16];
    #pragma unroll
    for (int q = 0; q < 4; ++q) {
        const int idx = t * 16 + q * 4;
        if (idx < nE) {  // nE % 4 == 0 always
            const int4 s4 = *reinterpret_cast<const int4*>(ei + e0 + idx);
            const int4 d4 = *reinterpret_cast<const int4*>(ei + N_EDGES + e0 + idx);
            srcs[q * 4 + 0] = s4.x; srcs[q * 4 + 1] = s4.y;
            srcs[q * 4 + 2] = s4.z; srcs[q * 4 + 3] = s4.w;
            dsts[q * 4 + 0] = d4.x; dsts[q * 4 + 1] = d4.y;
            dsts[q * 4 + 2] = d4.z; dsts[q * 4 + 3] = d4.w;
            atomicAdd(&hist[d4.x / NODES_PER_BKT], 1);
            atomicAdd(&hist[d4.y / NODES_PER_BKT], 1);
            atomicAdd(&hist[d4.z / NODES_PER_BKT], 1);
            atomicAdd(&hist[d4.w / NODES_PER_BKT], 1);
        } else {
            srcs[q*4+0]=srcs[q*4+1]=srcs[q*4+2]=srcs[q*4+3]=0;
            dsts[q*4+0]=dsts[q*4+1]=dsts[q*4+2]=dsts[q*4+3]=0;
        }
    }
    __syncthreads();

    // Exclusive scan of hist via per-wave shfl_up + cross-wave fixup (1 barrier).
    const int hv = hist[t];
    int v = hv;
    #pragma unroll
    for (int off = 1; off < 64; off <<= 1) {
        const int u = __shfl_up(v, off, 64);
        if (lane >= off) v += u;
    }
    if (lane == 63) wsum[wave] = v;
    __syncthreads();
    int prefix = 0;
    #pragma unroll
    for (int k = 0; k < 4; ++k) prefix += (k < wave) ? wsum[k] : 0;
    const int myExcl = v + prefix - hv;
    lexcl[t] = myExcl;
    lcur[t]  = myExcl;
    res[t]   = (hv > 0) ? atomicAdd(&cursor[t], hv) : 0;
    __syncthreads();

    // Local sort into stage (bucket-contiguous).
    #pragma unroll
    for (int q = 0; q < 16; ++q) {
        const int idx = t * 16 + q;
        if (idx < nE) {
            const int b = dsts[q] / NODES_PER_BKT;
            const int p = atomicAdd(&lcur[b], 1);
            stage[p] = ((unsigned)dsts[q] << 16) | (unsigned)srcs[q];
        }
    }
    __syncthreads();

    // Coalesced write-out at reserved offsets.
    for (int i = t; i < nE; i += 256) {
        const unsigned pv = stage[i];
        const int b = (int)(pv >> 16) / NODES_PER_BKT;
        const int p = res[b] + (i - lexcl[b]);
        if (p < BKT_CAP) binned[(size_t)b * BKT_CAP + p] = pv;
    }
}

// ---- pass 2: one block per bucket -> offs, csr_src (wave-scans, coalesced) ----
__global__ __launch_bounds__(256) void csr_build_kernel(
    const unsigned* __restrict__ binned,
    const int* __restrict__ cursor,
    int* __restrict__ offs,      // [N_NODES+1]
    int* __restrict__ csr_src)   // [N_EDGES]
{
    __shared__ int ldeg[NODES_PER_BKT];
    __shared__ int lcur[NODES_PER_BKT];
    __shared__ int wsum[4];
    __shared__ int stage_src[BKT_CAP];     // 16 KB

    const int b    = blockIdx.x;
    const int t    = threadIdx.x;
    const int wave = t >> 6;
    const int lane = t & 63;

    // ebase = sum of bucket counts below b: masked block-reduce (1 barrier).
    int contrib = (t < b) ? min(cursor[t], BKT_CAP) : 0;
    #pragma unroll
    for (int m = 1; m <= 32; m <<= 1) contrib += __shfl_xor(contrib, m, 64);
    if (lane == 0) wsum[wave] = contrib;
    if (t < NODES_PER_BKT) ldeg[t] = 0;
    __syncthreads();
    const int ebase = wsum[0] + wsum[1] + wsum[2] + wsum[3];

    const int cnt      = min(cursor[b], BKT_CAP);
    const int nodeBase = b * NODES_PER_BKT;

    unsigned pk[16];
    #pragma unroll
    for (int q = 0; q < 16; ++q) {
        const int i = t + q * 256;
        pk[q] = 0xffffffffu;
        if (i < cnt) {
            pk[q] = binned[(size_t)b * BKT_CAP + i];
            atomicAdd(&ldeg[(int)(pk[q] >> 16) - nodeBase], 1);
        }
    }
    __syncthreads();

    // Exclusive scan of ldeg (196 padded to 256) via shfl_up + fixup.
    const int dv = (t < NODES_PER_BKT) ? ldeg[t] : 0;
    int v = dv;
    #pragma unroll
    for (int off = 1; off < 64; off <<= 1) {
        const int u = __shfl_up(v, off, 64);
        if (lane >= off) v += u;
    }
    if (lane == 63) wsum[wave] = v;   // safe: previous wsum reads done (barrier above)
    __syncthreads();
    int prefix = 0;
    #pragma unroll
    for (int k = 0; k < 4; ++k) prefix += (k < wave) ? wsum[k] : 0;
    const int excl = v + prefix - dv;

    const int nNodes = min(N_NODES - nodeBase, NODES_PER_BKT);
    if (t < nNodes) {
        offs[nodeBase + t] = ebase + excl;
        lcur[t] = excl;
    }
    if (b == NBKT - 1 && t == 0) offs[N_NODES] = N_EDGES;
    __syncthreads();

    #pragma unroll
    for (int q = 0; q < 16; ++q) {
        const int i = t + q * 256;
        if (i < cnt) {
            const int loc = (int)(pk[q] >> 16) - nodeBase;
            const int p = atomicAdd(&lcur[loc], 1);
            stage_src[p] = (int)(pk[q] & 0xffffu);
        }
    }
    __syncthreads();

    for (int i = t; i < cnt; i += 256) {
        csr_src[ebase + i] = stage_src[i];
    }
}

// ---- pass 3 (fused): 512 threads/block, one wave per 4 consecutive nodes.
//      Prefetched offs + idx; register gather; single 4-node epilogue. ----
__global__ __launch_bounds__(512, 6) void gather_fused_kernel(
    const float* __restrict__ x,
    const int*   __restrict__ csr_src,
    const int*   __restrict__ offs,
    const float* __restrict__ W,
    float*       __restrict__ out)
{
    __shared__ float4 sW4[16][HID_CH];  // [k4][o] = W[o][4k4..4k4+3]; 32 KB
    __shared__ float4 sM[8][4][16];     // per-wave scaled means; 8 KB

    const int t = threadIdx.x;
    #pragma unroll
    for (int r = 0; r < 4; ++r) {
        const int i = t + r * 512;
        const int o = i >> 4, k4 = i & 15;
        sW4[k4][o] = *reinterpret_cast<const float4*>(W + (size_t)o * IN_CH + k4 * 4);
    }
    __syncthreads();   // last barrier in kernel; early return below is safe

    const int wave = t >> 6;
    const int lane = t & 63;
    const int grp  = lane >> 4;
    const int ch4  = lane & 15;
    const int wid  = blockIdx.x * 8 + wave;
    const int n0   = wid * 4;
    if (n0 >= N_NODES) return;

    // Prefetch the 5 offs values bounding this wave's 4 nodes.
    int ov = 0;
    if (lane < 5) ov = offs[min(n0 + lane, N_NODES)];
    const int s0 = __shfl(ov, 0, 64), s1 = __shfl(ov, 1, 64);
    const int s2 = __shfl(ov, 2, 64), s3 = __shfl(ov, 3, 64);
    const int s4 = __shfl(ov, 4, 64);

    // Issue all 4 nodes' first-chunk index loads before any gather math.
    int idxA = 0, idxB = 0, idxC = 0, idxD = 0;
    if (lane < s1 - s0) idxA = csr_src[s0 + lane];
    if (lane < s2 - s1) idxB = csr_src[s1 + lane];
    if (lane < s3 - s2) idxC = csr_src[s2 + lane];
    if (lane < s4 - s3) idxD = csr_src[s3 + lane];

#define GATHER_NODE(JJ, S, E, IDX0)                                                   \
    {                                                                                 \
        float a0 = 0.f, a1 = 0.f, a2 = 0.f, a3 = 0.f;                                 \
        int idxr = IDX0;                                                              \
        for (int base = (S); base < (E); base += 64) {                                \
            const int cnt = min((E) - base, 64);                                      \
            if (base != (S)) {                                                        \
                idxr = 0;                                                             \
                if (lane < cnt) idxr = csr_src[base + lane];                          \
            }                                                                         \
            const int nIt = (cnt + 15) >> 4;                                          \
            for (int ii = 0; ii < nIt; ++ii) {                                        \
                const int eb = ii * 16;                                               \
                const int e0 = eb + grp, e1 = e0 + 4, e2 = e0 + 8, e3 = e0 + 12;      \
                const int q0 = __shfl(idxr, e0 & 63, 64);                             \
                const int q1 = __shfl(idxr, e1 & 63, 64);                             \
                const int q2 = __shfl(idxr, e2 & 63, 64);                             \
                const int q3 = __shfl(idxr, e3 & 63, 64);                             \
                const float f0 = (e0 < cnt) ? 1.f : 0.f;                              \
                const float f1 = (e1 < cnt) ? 1.f : 0.f;                              \
                const float f2 = (e2 < cnt) ? 1.f : 0.f;                              \
                const float f3 = (e3 < cnt) ? 1.f : 0.f;                              \
                const float4 v0 = *reinterpret_cast<const float4*>(x + (size_t)q0 * IN_CH + ch4 * 4); \
                const float4 v1 = *reinterpret_cast<const float4*>(x + (size_t)q1 * IN_CH + ch4 * 4); \
                const float4 v2 = *reinterpret_cast<const float4*>(x + (size_t)q2 * IN_CH + ch4 * 4); \
                const float4 v3 = *reinterpret_cast<const float4*>(x + (size_t)q3 * IN_CH + ch4 * 4); \
                a0 = fmaf(f0, v0.x, a0); a1 = fmaf(f0, v0.y, a1);                     \
                a2 = fmaf(f0, v0.z, a2); a3 = fmaf(f0, v0.w, a3);                     \
                a0 = fmaf(f1, v1.x, a0); a1 = fmaf(f1, v1.y, a1);                     \
                a2 = fmaf(f1, v1.z, a2); a3 = fmaf(f1, v1.w, a3);                     \
                a0 = fmaf(f2, v2.x, a0); a1 = fmaf(f2, v2.y, a1);                     \
                a2 = fmaf(f2, v2.z, a2); a3 = fmaf(f2, v2.w, a3);                     \
                a0 = fmaf(f3, v3.x, a0); a1 = fmaf(f3, v3.y, a1);                     \
                a2 = fmaf(f3, v3.z, a2); a3 = fmaf(f3, v3.w, a3);                     \
            }                                                                         \
        }                                                                             \
        _Pragma("unroll")                                                             \
        for (int m = 16; m <= 32; m <<= 1) {                                          \
            a0 += __shfl_xor(a0, m, 64);                                              \
            a1 += __shfl_xor(a1, m, 64);                                              \
            a2 += __shfl_xor(a2, m, 64);                                              \
            a3 += __shfl_xor(a3, m, 64);                                              \
        }                                                                             \
        if (lane < 16) {                                                              \
            const float inv = 1.0f / fmaxf((float)((E) - (S)), 1.0f);                 \
            float4 r{a0 * inv, a1 * inv, a2 * inv, a3 * inv};                         \
            sM[wave][JJ][ch4] = r;                                                    \
        }                                                                             \
    }

    GATHER_NODE(0, s0, s1, idxA)
    GATHER_NODE(1, s1, s2, idxB)
    GATHER_NODE(2, s2, s3, idxC)
    GATHER_NODE(3, s3, s4, idxD)
#undef GATHER_NODE

    // Drain DS queue before reading sM (same-wave write->read); pin codegen.
    __asm__ volatile("s_waitcnt lgkmcnt(0)" ::: "memory");
    __builtin_amdgcn_sched_barrier(0);

    // Single epilogue for 4 nodes: W read once, 4 broadcast means.
    float acc[4][2] = {{0.f,0.f},{0.f,0.f},{0.f,0.f},{0.f,0.f}};
    #pragma unroll
    for (int k4 = 0; k4 < 16; ++k4) {
        const float4 w0 = sW4[k4][lane];
        const float4 w1 = sW4[k4][lane + 64];
        #pragma unroll
        for (int j = 0; j < 4; ++j) {
            const float4 a = sM[wave][j][k4];   // broadcast read
            acc[j][0] += a.x * w0.x + a.y * w0.y + a.z * w0.z + a.w * w0.w;
            acc[j][1] += a.x * w1.x + a.y * w1.y + a.z * w1.z + a.w * w1.w;
        }
    }
    #pragma unroll
    for (int j = 0; j < 4; ++j) {
        const int n = n0 + j;
        if (n < N_NODES) {
            const size_t row = (size_t)n * HID_CH;
            out[row + lane]      = acc[j][0];
            out[row + 64 + lane] = acc[j][1];
        }
    }
}

extern "C" void kernel_launch(void* const* d_in, const int* in_sizes, int n_in,
                              void* d_out, int out_size, void* d_ws, size_t ws_size,
                              hipStream_t stream) {
    const float* x   = (const float*)d_in[0];
    const int*   ei  = (const int*)  d_in[1];
    const float* W   = (const float*)d_in[2];
    float*       out = (float*)d_out;

    // ws layout: binned (4 MB), cursor, offs (padded to 50004), csr_src
    unsigned* binned = (unsigned*)d_ws;                    // NBKT*BKT_CAP
    int* cursor  = (int*)(binned + (size_t)NBKT * BKT_CAP);
    int* offs    = cursor + NBKT;
    int* csr_src = offs + 50004;

    hipMemsetAsync(cursor, 0, NBKT * sizeof(int), stream);
    bin_kernel<<<NBIN, 256, 0, stream>>>(ei, cursor, binned);
    csr_build_kernel<<<NBKT, 256, 0, stream>>>(binned, cursor, offs, csr_src);
    gather_fused_kernel<<<(N_NODES + 31) / 32, 512, 0, stream>>>(x, csr_src, offs, W, out);
}

// Round 13
// 133.687 us; speedup vs baseline: 4.1728x; 4.1728x over previous
//
#include <hip/hip_runtime.h>

// GraphSAGE mean-aggregate + linear (no bias): out = segment_mean(x[src] by dst) @ W^T
// x: [50000, 64] f32, edge_index: [2, 800000] int32, W: [128, 64] f32,
// out: [50000, 128] f32.
//
// Pipeline (4 dispatches):
//   memset(cursor) -> bin (bucket sort by dst/196, 32-bit packed (dst<<16)|src,
//   wave-scans) -> csr_build (per-bucket local CSR, wave-scans) -> gather_fused
//   (R11-proven: 256 threads, one wave per 4 nodes, register gather + butterfly,
//    mean + W^T epilogue from LDS-staged W).

constexpr int N_NODES = 50000;
constexpr int N_EDGES = 800000;
constexpr int IN_CH   = 64;
constexpr int HID_CH  = 128;

constexpr int NBKT          = 256;
constexpr int NODES_PER_BKT = 196;   // 256*196 = 50176 >= 50000; bucket = dst/196
constexpr int BKT_CAP       = 4096;  // mean 3125, sigma ~56 -> +17 sigma headroom
constexpr int CHUNK         = 4096;  // edges per binning block
constexpr int NBIN          = (N_EDGES + CHUNK - 1) / CHUNK;  // 196

// ---- pass 1: bucket-bin edges, 32-bit packed (dst<<16)|src ----
__global__ __launch_bounds__(256) void bin_kernel(
    const int* __restrict__ ei,
    int* __restrict__ cursor,              // [NBKT], zeroed
    unsigned* __restrict__ binned)         // [NBKT][BKT_CAP]
{
    __shared__ int hist[NBKT];
    __shared__ int lexcl[NBKT];
    __shared__ int lcur[NBKT];
    __shared__ int res[NBKT];
    __shared__ int wsum[4];
    __shared__ unsigned stage[CHUNK];      // 16 KB

    const int t    = threadIdx.x;
    const int wave = t >> 6;
    const int lane = t & 63;
    const int e0   = blockIdx.x * CHUNK;
    const int nE   = min(N_EDGES - e0, CHUNK);

    hist[t] = 0;
    __syncthreads();

    int srcs[16], dsts[16];
    #pragma unroll
    for (int q = 0; q < 4; ++q) {
        const int idx = t * 16 + q * 4;
        if (idx < nE) {  // nE % 4 == 0 always
            const int4 s4 = *reinterpret_cast<const int4*>(ei + e0 + idx);
            const int4 d4 = *reinterpret_cast<const int4*>(ei + N_EDGES + e0 + idx);
            srcs[q * 4 + 0] = s4.x; srcs[q * 4 + 1] = s4.y;
            srcs[q * 4 + 2] = s4.z; srcs[q * 4 + 3] = s4.w;
            dsts[q * 4 + 0] = d4.x; dsts[q * 4 + 1] = d4.y;
            dsts[q * 4 + 2] = d4.z; dsts[q * 4 + 3] = d4.w;
            atomicAdd(&hist[d4.x / NODES_PER_BKT], 1);
            atomicAdd(&hist[d4.y / NODES_PER_BKT], 1);
            atomicAdd(&hist[d4.z / NODES_PER_BKT], 1);
            atomicAdd(&hist[d4.w / NODES_PER_BKT], 1);
        } else {
            srcs[q*4+0]=srcs[q*4+1]=srcs[q*4+2]=srcs[q*4+3]=0;
            dsts[q*4+0]=dsts[q*4+1]=dsts[q*4+2]=dsts[q*4+3]=0;
        }
    }
    __syncthreads();

    // Exclusive scan of hist via per-wave shfl_up + cross-wave fixup (1 barrier).
    const int hv = hist[t];
    int v = hv;
    #pragma unroll
    for (int off = 1; off < 64; off <<= 1) {
        const int u = __shfl_up(v, off, 64);
        if (lane >= off) v += u;
    }
    if (lane == 63) wsum[wave] = v;
    __syncthreads();
    int prefix = 0;
    #pragma unroll
    for (int k = 0; k < 4; ++k) prefix += (k < wave) ? wsum[k] : 0;
    const int myExcl = v + prefix - hv;
    lexcl[t] = myExcl;
    lcur[t]  = myExcl;
    res[t]   = (hv > 0) ? atomicAdd(&cursor[t], hv) : 0;
    __syncthreads();

    // Local sort into stage (bucket-contiguous).
    #pragma unroll
    for (int q = 0; q < 16; ++q) {
        const int idx = t * 16 + q;
        if (idx < nE) {
            const int b = dsts[q] / NODES_PER_BKT;
            const int p = atomicAdd(&lcur[b], 1);
            stage[p] = ((unsigned)dsts[q] << 16) | (unsigned)srcs[q];
        }
    }
    __syncthreads();

    // Coalesced write-out at reserved offsets.
    for (int i = t; i < nE; i += 256) {
        const unsigned pv = stage[i];
        const int b = (int)(pv >> 16) / NODES_PER_BKT;
        const int p = res[b] + (i - lexcl[b]);
        if (p < BKT_CAP) binned[(size_t)b * BKT_CAP + p] = pv;
    }
}

// ---- pass 2: one block per bucket -> offs, csr_src (wave-scans, coalesced) ----
__global__ __launch_bounds__(256) void csr_build_kernel(
    const unsigned* __restrict__ binned,
    const int* __restrict__ cursor,
    int* __restrict__ offs,      // [N_NODES+1]
    int* __restrict__ csr_src)   // [N_EDGES]
{
    __shared__ int ldeg[NODES_PER_BKT];
    __shared__ int lcur[NODES_PER_BKT];
    __shared__ int wsum[4];
    __shared__ int stage_src[BKT_CAP];     // 16 KB

    const int b    = blockIdx.x;
    const int t    = threadIdx.x;
    const int wave = t >> 6;
    const int lane = t & 63;

    // ebase = sum of bucket counts below b: masked block-reduce (1 barrier).
    int contrib = (t < b) ? min(cursor[t], BKT_CAP) : 0;
    #pragma unroll
    for (int m = 1; m <= 32; m <<= 1) contrib += __shfl_xor(contrib, m, 64);
    if (lane == 0) wsum[wave] = contrib;
    if (t < NODES_PER_BKT) ldeg[t] = 0;
    __syncthreads();
    const int ebase = wsum[0] + wsum[1] + wsum[2] + wsum[3];

    const int cnt      = min(cursor[b], BKT_CAP);
    const int nodeBase = b * NODES_PER_BKT;

    unsigned pk[16];
    #pragma unroll
    for (int q = 0; q < 16; ++q) {
        const int i = t + q * 256;
        pk[q] = 0xffffffffu;
        if (i < cnt) {
            pk[q] = binned[(size_t)b * BKT_CAP + i];
            atomicAdd(&ldeg[(int)(pk[q] >> 16) - nodeBase], 1);
        }
    }
    __syncthreads();

    // Exclusive scan of ldeg (196 padded to 256) via shfl_up + fixup.
    const int dv = (t < NODES_PER_BKT) ? ldeg[t] : 0;
    int v = dv;
    #pragma unroll
    for (int off = 1; off < 64; off <<= 1) {
        const int u = __shfl_up(v, off, 64);
        if (lane >= off) v += u;
    }
    if (lane == 63) wsum[wave] = v;   // safe: previous wsum reads done (barrier above)
    __syncthreads();
    int prefix = 0;
    #pragma unroll
    for (int k = 0; k < 4; ++k) prefix += (k < wave) ? wsum[k] : 0;
    const int excl = v + prefix - dv;

    const int nNodes = min(N_NODES - nodeBase, NODES_PER_BKT);
    if (t < nNodes) {
        offs[nodeBase + t] = ebase + excl;
        lcur[t] = excl;
    }
    if (b == NBKT - 1 && t == 0) offs[N_NODES] = N_EDGES;
    __syncthreads();

    #pragma unroll
    for (int q = 0; q < 16; ++q) {
        const int i = t + q * 256;
        if (i < cnt) {
            const int loc = (int)(pk[q] >> 16) - nodeBase;
            const int p = atomicAdd(&lcur[loc], 1);
            stage_src[p] = (int)(pk[q] & 0xffffu);
        }
    }
    __syncthreads();

    for (int i = t; i < cnt; i += 256) {
        csr_src[ebase + i] = stage_src[i];
    }
}

// ---- pass 3 (fused, R11-proven): one wave per 4 consecutive nodes. Register
//      gather (16 lanes x float4 per row, 16 edges in flight) + butterfly
//      merge, then mean + W^T epilogue from LDS-staged W. ----
__global__ __launch_bounds__(256) void gather_fused_kernel(
    const float* __restrict__ x,
    const int*   __restrict__ csr_src,
    const int*   __restrict__ offs,
    const float* __restrict__ W,
    float*       __restrict__ out)
{
    __shared__ float4 sW4[16][HID_CH + 1];  // [k4][o] = W[o][4k4..4k4+3]; 33 KB
    __shared__ float4 sM[4][16];            // per-wave scaled mean staging

    const int t = threadIdx.x;
    #pragma unroll
    for (int r = 0; r < 8; ++r) {
        const int i = t + r * 256;
        const int o = i >> 4, k4 = i & 15;
        sW4[k4][o] = *reinterpret_cast<const float4*>(W + (size_t)o * IN_CH + k4 * 4);
    }
    __syncthreads();

    const int wave = t >> 6;
    const int lane = t & 63;
    const int grp  = lane >> 4;
    const int ch4  = lane & 15;
    const int wid  = blockIdx.x * 4 + wave;   // grid 3125 -> 12500 waves, 4 nodes each

    #pragma unroll 1
    for (int j = 0; j < 4; ++j) {
        const int n = wid * 4 + j;            // consecutive nodes per wave
        const int start = offs[n];
        const int end   = offs[n + 1];
        const int d     = end - start;

        float a0 = 0.f, a1 = 0.f, a2 = 0.f, a3 = 0.f;
        for (int base = start; base < end; base += 64) {
            const int cnt = min(end - base, 64);
            int idx = 0;
            if (lane < cnt) idx = csr_src[base + lane];
            const int nIt = (cnt + 3) >> 2;
            for (int i = 0; i < nIt; i += 4) {
                const int e0 = 4 * i + grp;
                const int e1 = e0 + 4, e2 = e0 + 8, e3 = e0 + 12;
                const int s0 = __shfl(idx, e0 & 63, 64);
                const int s1 = __shfl(idx, e1 & 63, 64);
                const int s2 = __shfl(idx, e2 & 63, 64);
                const int s3 = __shfl(idx, e3 & 63, 64);
                const float f0 = (e0 < cnt) ? 1.f : 0.f;
                const float f1 = (e1 < cnt) ? 1.f : 0.f;
                const float f2 = (e2 < cnt) ? 1.f : 0.f;
                const float f3 = (e3 < cnt) ? 1.f : 0.f;
                const float4 v0 = *reinterpret_cast<const float4*>(x + (size_t)s0 * IN_CH + ch4 * 4);
                const float4 v1 = *reinterpret_cast<const float4*>(x + (size_t)s1 * IN_CH + ch4 * 4);
                const float4 v2 = *reinterpret_cast<const float4*>(x + (size_t)s2 * IN_CH + ch4 * 4);
                const float4 v3 = *reinterpret_cast<const float4*>(x + (size_t)s3 * IN_CH + ch4 * 4);
                a0 = fmaf(f0, v0.x, a0); a1 = fmaf(f0, v0.y, a1);
                a2 = fmaf(f0, v0.z, a2); a3 = fmaf(f0, v0.w, a3);
                a0 = fmaf(f1, v1.x, a0); a1 = fmaf(f1, v1.y, a1);
                a2 = fmaf(f1, v1.z, a2); a3 = fmaf(f1, v1.w, a3);
                a0 = fmaf(f2, v2.x, a0); a1 = fmaf(f2, v2.y, a1);
                a2 = fmaf(f2, v2.z, a2); a3 = fmaf(f2, v2.w, a3);
                a0 = fmaf(f3, v3.x, a0); a1 = fmaf(f3, v3.y, a1);
                a2 = fmaf(f3, v3.z, a2); a3 = fmaf(f3, v3.w, a3);
            }
        }
        // Merge the 4 edge groups: lanes 0-15 end with full channel sums.
        #pragma unroll
        for (int m = 16; m <= 32; m <<= 1) {
            a0 += __shfl_xor(a0, m, 64);
            a1 += __shfl_xor(a1, m, 64);
            a2 += __shfl_xor(a2, m, 64);
            a3 += __shfl_xor(a3, m, 64);
        }
        const float inv = 1.0f / fmaxf((float)d, 1.0f);
        if (lane < 16) {
            float4 r{a0 * inv, a1 * inv, a2 * inv, a3 * inv};
            sM[wave][ch4] = r;
        }
        // Same-wave LDS write -> read: drain DS queue; memory clobber orders
        // the following ds_reads; sched_barrier pins codegen.
        __asm__ volatile("s_waitcnt lgkmcnt(0)" ::: "memory");
        __builtin_amdgcn_sched_barrier(0);

        float o0 = 0.f, o1 = 0.f;
        #pragma unroll
        for (int k4 = 0; k4 < 16; ++k4) {
            const float4 w0 = sW4[k4][lane];
            const float4 w1 = sW4[k4][lane + 64];
            const float4 a  = sM[wave][k4];   // broadcast read
            o0 += a.x * w0.x + a.y * w0.y + a.z * w0.z + a.w * w0.w;
            o1 += a.x * w1.x + a.y * w1.y + a.z * w1.z + a.w * w1.w;
        }
        const size_t row = (size_t)n * HID_CH;
        out[row + lane]      = o0;
        out[row + 64 + lane] = o1;
    }
}

extern "C" void kernel_launch(void* const* d_in, const int* in_sizes, int n_in,
                              void* d_out, int out_size, void* d_ws, size_t ws_size,
                              hipStream_t stream) {
    const float* x   = (const float*)d_in[0];
    const int*   ei  = (const int*)  d_in[1];
    const float* W   = (const float*)d_in[2];
    float*       out = (float*)d_out;

    // ws layout: binned (4 MB), cursor, offs (padded to 50004), csr_src
    unsigned* binned = (unsigned*)d_ws;                    // NBKT*BKT_CAP
    int* cursor  = (int*)(binned + (size_t)NBKT * BKT_CAP);
    int* offs    = cursor + NBKT;
    int* csr_src = offs + 50004;

    hipMemsetAsync(cursor, 0, NBKT * sizeof(int), stream);
    bin_kernel<<<NBIN, 256, 0, stream>>>(ei, cursor, binned);
    csr_build_kernel<<<NBKT, 256, 0, stream>>>(binned, cursor, offs, csr_src);
    gather_fused_kernel<<<N_NODES / 16, 256, 0, stream>>>(x, csr_src, offs, W, out);
}

// Round 14
// 128.267 us; speedup vs baseline: 4.3491x; 1.0423x over previous
//
#include <hip/hip_runtime.h>

// GraphSAGE mean-aggregate + linear (no bias): out = segment_mean(x[src] by dst) @ W^T
// x: [50000, 64] f32, edge_index: [2, 800000] int32, W: [128, 64] f32,
// out: [50000, 128] f32.
//
// Pipeline (4 dispatches):
//   memset(cursor) -> bin (bucket sort by dst/196, 32-bit packed (dst<<16)|src,
//   wave-scans) -> csr_build (per-bucket local CSR, wave-scans) -> gather_fused
//   (512 threads / 8 waves share one 32 KB W tile; per-wave code identical to
//    the R13-proven 4-nodes-per-wave register gather + per-node epilogue).

constexpr int N_NODES = 50000;
constexpr int N_EDGES = 800000;
constexpr int IN_CH   = 64;
constexpr int HID_CH  = 128;

constexpr int NBKT          = 256;
constexpr int NODES_PER_BKT = 196;   // 256*196 = 50176 >= 50000; bucket = dst/196
constexpr int BKT_CAP       = 4096;  // mean 3125, sigma ~56 -> +17 sigma headroom
constexpr int CHUNK         = 4096;  // edges per binning block
constexpr int NBIN          = (N_EDGES + CHUNK - 1) / CHUNK;  // 196

// ---- pass 1: bucket-bin edges, 32-bit packed (dst<<16)|src ----
__global__ __launch_bounds__(256) void bin_kernel(
    const int* __restrict__ ei,
    int* __restrict__ cursor,              // [NBKT], zeroed
    unsigned* __restrict__ binned)         // [NBKT][BKT_CAP]
{
    __shared__ int hist[NBKT];
    __shared__ int lexcl[NBKT];
    __shared__ int lcur[NBKT];
    __shared__ int res[NBKT];
    __shared__ int wsum[4];
    __shared__ unsigned stage[CHUNK];      // 16 KB

    const int t    = threadIdx.x;
    const int wave = t >> 6;
    const int lane = t & 63;
    const int e0   = blockIdx.x * CHUNK;
    const int nE   = min(N_EDGES - e0, CHUNK);

    hist[t] = 0;
    __syncthreads();

    int srcs[16], dsts[16];
    #pragma unroll
    for (int q = 0; q < 4; ++q) {
        const int idx = t * 16 + q * 4;
        if (idx < nE) {  // nE % 4 == 0 always
            const int4 s4 = *reinterpret_cast<const int4*>(ei + e0 + idx);
            const int4 d4 = *reinterpret_cast<const int4*>(ei + N_EDGES + e0 + idx);
            srcs[q * 4 + 0] = s4.x; srcs[q * 4 + 1] = s4.y;
            srcs[q * 4 + 2] = s4.z; srcs[q * 4 + 3] = s4.w;
            dsts[q * 4 + 0] = d4.x; dsts[q * 4 + 1] = d4.y;
            dsts[q * 4 + 2] = d4.z; dsts[q * 4 + 3] = d4.w;
            atomicAdd(&hist[d4.x / NODES_PER_BKT], 1);
            atomicAdd(&hist[d4.y / NODES_PER_BKT], 1);
            atomicAdd(&hist[d4.z / NODES_PER_BKT], 1);
            atomicAdd(&hist[d4.w / NODES_PER_BKT], 1);
        } else {
            srcs[q*4+0]=srcs[q*4+1]=srcs[q*4+2]=srcs[q*4+3]=0;
            dsts[q*4+0]=dsts[q*4+1]=dsts[q*4+2]=dsts[q*4+3]=0;
        }
    }
    __syncthreads();

    // Exclusive scan of hist via per-wave shfl_up + cross-wave fixup (1 barrier).
    const int hv = hist[t];
    int v = hv;
    #pragma unroll
    for (int off = 1; off < 64; off <<= 1) {
        const int u = __shfl_up(v, off, 64);
        if (lane >= off) v += u;
    }
    if (lane == 63) wsum[wave] = v;
    __syncthreads();
    int prefix = 0;
    #pragma unroll
    for (int k = 0; k < 4; ++k) prefix += (k < wave) ? wsum[k] : 0;
    const int myExcl = v + prefix - hv;
    lexcl[t] = myExcl;
    lcur[t]  = myExcl;
    res[t]   = (hv > 0) ? atomicAdd(&cursor[t], hv) : 0;
    __syncthreads();

    // Local sort into stage (bucket-contiguous).
    #pragma unroll
    for (int q = 0; q < 16; ++q) {
        const int idx = t * 16 + q;
        if (idx < nE) {
            const int b = dsts[q] / NODES_PER_BKT;
            const int p = atomicAdd(&lcur[b], 1);
            stage[p] = ((unsigned)dsts[q] << 16) | (unsigned)srcs[q];
        }
    }
    __syncthreads();

    // Coalesced write-out at reserved offsets.
    for (int i = t; i < nE; i += 256) {
        const unsigned pv = stage[i];
        const int b = (int)(pv >> 16) / NODES_PER_BKT;
        const int p = res[b] + (i - lexcl[b]);
        if (p < BKT_CAP) binned[(size_t)b * BKT_CAP + p] = pv;
    }
}

// ---- pass 2: one block per bucket -> offs, csr_src (wave-scans, coalesced) ----
__global__ __launch_bounds__(256) void csr_build_kernel(
    const unsigned* __restrict__ binned,
    const int* __restrict__ cursor,
    int* __restrict__ offs,      // [N_NODES+1]
    int* __restrict__ csr_src)   // [N_EDGES]
{
    __shared__ int ldeg[NODES_PER_BKT];
    __shared__ int lcur[NODES_PER_BKT];
    __shared__ int wsum[4];
    __shared__ int stage_src[BKT_CAP];     // 16 KB

    const int b    = blockIdx.x;
    const int t    = threadIdx.x;
    const int wave = t >> 6;
    const int lane = t & 63;

    // ebase = sum of bucket counts below b: masked block-reduce (1 barrier).
    int contrib = (t < b) ? min(cursor[t], BKT_CAP) : 0;
    #pragma unroll
    for (int m = 1; m <= 32; m <<= 1) contrib += __shfl_xor(contrib, m, 64);
    if (lane == 0) wsum[wave] = contrib;
    if (t < NODES_PER_BKT) ldeg[t] = 0;
    __syncthreads();
    const int ebase = wsum[0] + wsum[1] + wsum[2] + wsum[3];

    const int cnt      = min(cursor[b], BKT_CAP);
    const int nodeBase = b * NODES_PER_BKT;

    unsigned pk[16];
    #pragma unroll
    for (int q = 0; q < 16; ++q) {
        const int i = t + q * 256;
        pk[q] = 0xffffffffu;
        if (i < cnt) {
            pk[q] = binned[(size_t)b * BKT_CAP + i];
            atomicAdd(&ldeg[(int)(pk[q] >> 16) - nodeBase], 1);
        }
    }
    __syncthreads();

    // Exclusive scan of ldeg (196 padded to 256) via shfl_up + fixup.
    const int dv = (t < NODES_PER_BKT) ? ldeg[t] : 0;
    int v = dv;
    #pragma unroll
    for (int off = 1; off < 64; off <<= 1) {
        const int u = __shfl_up(v, off, 64);
        if (lane >= off) v += u;
    }
    if (lane == 63) wsum[wave] = v;   // safe: previous wsum reads done (barrier above)
    __syncthreads();
    int prefix = 0;
    #pragma unroll
    for (int k = 0; k < 4; ++k) prefix += (k < wave) ? wsum[k] : 0;
    const int excl = v + prefix - dv;

    const int nNodes = min(N_NODES - nodeBase, NODES_PER_BKT);
    if (t < nNodes) {
        offs[nodeBase + t] = ebase + excl;
        lcur[t] = excl;
    }
    if (b == NBKT - 1 && t == 0) offs[N_NODES] = N_EDGES;
    __syncthreads();

    #pragma unroll
    for (int q = 0; q < 16; ++q) {
        const int i = t + q * 256;
        if (i < cnt) {
            const int loc = (int)(pk[q] >> 16) - nodeBase;
            const int p = atomicAdd(&lcur[loc], 1);
            stage_src[p] = (int)(pk[q] & 0xffffu);
        }
    }
    __syncthreads();

    for (int i = t; i < cnt; i += 256) {
        csr_src[ebase + i] = stage_src[i];
    }
}

// ---- pass 3 (fused): 512 threads / 8 waves share one 32 KB W tile.
//      Per-wave: 4 consecutive nodes, register gather (16 lanes x float4,
//      16 edges in flight) + butterfly merge, per-node mean+W^T epilogue. ----
__global__ __launch_bounds__(512, 8) void gather_fused_kernel(
    const float* __restrict__ x,
    const int*   __restrict__ csr_src,
    const int*   __restrict__ offs,
    const float* __restrict__ W,
    float*       __restrict__ out)
{
    __shared__ float4 sW4[16][HID_CH];  // [k4][o] = W[o][4k4..4k4+3]; 32 KB (row-consecutive reads: no pad needed)
    __shared__ float4 sM[8][16];        // per-wave scaled mean staging; 2 KB

    const int t = threadIdx.x;
    #pragma unroll
    for (int r = 0; r < 4; ++r) {
        const int i = t + r * 512;
        const int o = i >> 4, k4 = i & 15;
        sW4[k4][o] = *reinterpret_cast<const float4*>(W + (size_t)o * IN_CH + k4 * 4);
    }
    __syncthreads();

    const int wave = t >> 6;
    const int lane = t & 63;
    const int grp  = lane >> 4;
    const int ch4  = lane & 15;
    const int wid  = blockIdx.x * 8 + wave;   // grid 1563 -> 12504 waves, 4 nodes each

    #pragma unroll 1
    for (int j = 0; j < 4; ++j) {
        const int n = wid * 4 + j;            // consecutive nodes per wave
        if (n >= N_NODES) break;              // wave-uniform
        const int start = offs[n];
        const int end   = offs[n + 1];
        const int d     = end - start;

        float a0 = 0.f, a1 = 0.f, a2 = 0.f, a3 = 0.f;
        for (int base = start; base < end; base += 64) {
            const int cnt = min(end - base, 64);
            int idx = 0;
            if (lane < cnt) idx = csr_src[base + lane];
            const int nIt = (cnt + 3) >> 2;
            for (int i = 0; i < nIt; i += 4) {
                const int e0 = 4 * i + grp;
                const int e1 = e0 + 4, e2 = e0 + 8, e3 = e0 + 12;
                const int s0 = __shfl(idx, e0 & 63, 64);
                const int s1 = __shfl(idx, e1 & 63, 64);
                const int s2 = __shfl(idx, e2 & 63, 64);
                const int s3 = __shfl(idx, e3 & 63, 64);
                const float f0 = (e0 < cnt) ? 1.f : 0.f;
                const float f1 = (e1 < cnt) ? 1.f : 0.f;
                const float f2 = (e2 < cnt) ? 1.f : 0.f;
                const float f3 = (e3 < cnt) ? 1.f : 0.f;
                const float4 v0 = *reinterpret_cast<const float4*>(x + (size_t)s0 * IN_CH + ch4 * 4);
                const float4 v1 = *reinterpret_cast<const float4*>(x + (size_t)s1 * IN_CH + ch4 * 4);
                const float4 v2 = *reinterpret_cast<const float4*>(x + (size_t)s2 * IN_CH + ch4 * 4);
                const float4 v3 = *reinterpret_cast<const float4*>(x + (size_t)s3 * IN_CH + ch4 * 4);
                a0 = fmaf(f0, v0.x, a0); a1 = fmaf(f0, v0.y, a1);
                a2 = fmaf(f0, v0.z, a2); a3 = fmaf(f0, v0.w, a3);
                a0 = fmaf(f1, v1.x, a0); a1 = fmaf(f1, v1.y, a1);
                a2 = fmaf(f1, v1.z, a2); a3 = fmaf(f1, v1.w, a3);
                a0 = fmaf(f2, v2.x, a0); a1 = fmaf(f2, v2.y, a1);
                a2 = fmaf(f2, v2.z, a2); a3 = fmaf(f2, v2.w, a3);
                a0 = fmaf(f3, v3.x, a0); a1 = fmaf(f3, v3.y, a1);
                a2 = fmaf(f3, v3.z, a2); a3 = fmaf(f3, v3.w, a3);
            }
        }
        // Merge the 4 edge groups: lanes 0-15 end with full channel sums.
        #pragma unroll
        for (int m = 16; m <= 32; m <<= 1) {
            a0 += __shfl_xor(a0, m, 64);
            a1 += __shfl_xor(a1, m, 64);
            a2 += __shfl_xor(a2, m, 64);
            a3 += __shfl_xor(a3, m, 64);
        }
        const float inv = 1.0f / fmaxf((float)d, 1.0f);
        if (lane < 16) {
            float4 r{a0 * inv, a1 * inv, a2 * inv, a3 * inv};
            sM[wave][ch4] = r;
        }
        // Same-wave LDS write -> read: drain DS queue; memory clobber orders
        // the following ds_reads; sched_barrier pins codegen.
        __asm__ volatile("s_waitcnt lgkmcnt(0)" ::: "memory");
        __builtin_amdgcn_sched_barrier(0);

        float o0 = 0.f, o1 = 0.f;
        #pragma unroll
        for (int k4 = 0; k4 < 16; ++k4) {
            const float4 w0 = sW4[k4][lane];
            const float4 w1 = sW4[k4][lane + 64];
            const float4 a  = sM[wave][k4];   // broadcast read
            o0 += a.x * w0.x + a.y * w0.y + a.z * w0.z + a.w * w0.w;
            o1 += a.x * w1.x + a.y * w1.y + a.z * w1.z + a.w * w1.w;
        }
        const size_t row = (size_t)n * HID_CH;
        out[row + lane]      = o0;
        out[row + 64 + lane] = o1;
    }
}

extern "C" void kernel_launch(void* const* d_in, const int* in_sizes, int n_in,
                              void* d_out, int out_size, void* d_ws, size_t ws_size,
                              hipStream_t stream) {
    const float* x   = (const float*)d_in[0];
    const int*   ei  = (const int*)  d_in[1];
    const float* W   = (const float*)d_in[2];
    float*       out = (float*)d_out;

    // ws layout: binned (4 MB), cursor, offs (padded to 50004), csr_src
    unsigned* binned = (unsigned*)d_ws;                    // NBKT*BKT_CAP
    int* cursor  = (int*)(binned + (size_t)NBKT * BKT_CAP);
    int* offs    = cursor + NBKT;
    int* csr_src = offs + 50004;

    hipMemsetAsync(cursor, 0, NBKT * sizeof(int), stream);
    bin_kernel<<<NBIN, 256, 0, stream>>>(ei, cursor, binned);
    csr_build_kernel<<<NBKT, 256, 0, stream>>>(binned, cursor, offs, csr_src);
    // 8 waves/block x 4 nodes/wave = 32 nodes/block -> 1563 blocks
    gather_fused_kernel<<<(N_NODES + 31) / 32, 512, 0, stream>>>(x, csr_src, offs, W, out);
}